// Round 8
// baseline (196.831 us; speedup 1.0000x reference)
//
#include <hip/hip_runtime.h>
#include <hip/hip_fp16.h>

typedef __attribute__((ext_vector_type(8)))  _Float16 half8v;  // 8 f16 = 4 VGPR
typedef __attribute__((ext_vector_type(16))) float    f32x16;

// bswz element offsets: L0 17 steps, L1/L2/L3 66 steps, 512 f16/step
// [0, 8704) [8704, 42496) [42496, 76288) [76288, 110080)
static constexpr int BSWZ_TOT = 110080;

struct Prm {
    const float* x;
    const float* w2[4]; const float* b2[4];
    const float* root0; const float* bias0;
    _Float16* xin;   // N x 8 f16 (x[:,4:10], zero-padded)
    _Float16* bswz;  // all 4 layers' B fragments
    float* agg0;     // N x 32 f32, init = bias0 + x[:,4:10] @ root0
    int N;
};

// ---------------------------------------------------------------------------
// prep: [0,430) build bswz ; [430,430+NB8) pack xin ; rest init agg0.
// ---------------------------------------------------------------------------
__global__ __launch_bounds__(256) void prep(Prm p, int NB8, int NBN)
{
    int b = blockIdx.x;
    if (b < 430) {                                   // ---- bswz ----
        int i = b * 256 + threadIdx.x;               // < 110080 exactly
        int layer, base, INP, IN_C, OUT_C;
        if (i < 8704)       { layer = 0; base = 0;     INP = 8;  IN_C = 6;  OUT_C = 32; }
        else if (i < 42496) { layer = 1; base = 8704;  INP = 32; IN_C = 32; OUT_C = 32; }
        else if (i < 76288) { layer = 2; base = 42496; INP = 32; IN_C = 32; OUT_C = 32; }
        else                { layer = 3; base = 76288; INP = 32; IN_C = 32; OUT_C = 2;  }
        int t2 = i - base;
        int j = t2 & 7, l = (t2 >> 3) & 63, t = t2 >> 9;
        int g = l >> 5, o = l & 31;
        int S_MAIN = 2 * INP;
        float v = 0.f;
        if (t < S_MAIN) {
            int kap = 16 * t + 8 * g + j;
            int k  = (INP == 8) ? (kap >> 3) : (kap >> 5);
            int ii = (INP == 8) ? (kap & 7)  : (kap & 31);
            if (ii < IN_C && o < OUT_C)
                v = p.w2[layer][(size_t)k * (IN_C * OUT_C) + ii * OUT_C + o];
        } else {
            int ii = 16 * (t - S_MAIN) + 8 * g + j;
            if (ii < IN_C && o < OUT_C)
                v = p.b2[layer][ii * OUT_C + o];
        }
        p.bswz[i] = (_Float16)v;
    } else if (b < 430 + NB8) {                      // ---- pack xin ----
        int i = (b - 430) * 256 + threadIdx.x;
        if (i < p.N * 8) {
            int v = i >> 3, c = i & 7;
            float val = (c < 6) ? p.x[(size_t)v * 10 + 4 + c] : 0.f;
            p.xin[i] = (_Float16)val;
        }
    } else {                                         // ---- agg0 init ----
        int v = (b - 430 - NB8) * 256 + threadIdx.x;
        if (v < p.N) {
            const float* xp = p.x + (size_t)v * 10 + 4;
            float xv[6];
            #pragma unroll
            for (int i = 0; i < 6; ++i) xv[i] = xp[i];
            float4 o4[8];
            #pragma unroll
            for (int q = 0; q < 8; ++q) {
                #pragma unroll
                for (int m = 0; m < 4; ++m) {
                    int o = 4 * q + m;
                    float a = p.bias0[o];
                    #pragma unroll
                    for (int i = 0; i < 6; ++i)
                        a = fmaf(xv[i], p.root0[i * 32 + o], a);
                    ((float*)&o4[q])[m] = a;
                }
            }
            float4* ap = (float4*)(p.agg0 + (size_t)v * 32);
            #pragma unroll
            for (int q = 0; q < 8; ++q) ap[q] = o4[q];
        }
    }
}

// ---------------------------------------------------------------------------
// Edge kernel, ET edge-tiles per wave (wave = 32*ET edges): each B fragment
// is loaded ONCE and reused for ET MFMAs -> B-restream traffic / ET.
// A-fragments via packed f16 mul.  C layout (dtype-independent):
//   col = lane&31 = o, row = (r&3)+8*(r>>2)+4*(lane>>5).
// Epilogue: f32 atomics into agg (pre-initialized with node term + bias).
// ---------------------------------------------------------------------------
template<int INP, int OUT_C, int ET>
__global__ __launch_bounds__(256) void edge(
    const _Float16* __restrict__ feat,
    const int*      __restrict__ src,
    const int*      __restrict__ dst,
    const float*    __restrict__ ea,
    const float*    __restrict__ w1,     // (4,32) row-major
    const float*    __restrict__ b1,     // (32)
    const _Float16* __restrict__ bswz,
    float* __restrict__ agg,             // row stride OUT_C
    int E)
{
    const int lane = threadIdx.x & 63;
    const int wid  = (blockIdx.x * 256 + threadIdx.x) >> 6;
    const int e0   = wid * (32 * ET);
    if (e0 >= E) return;
    const int g = lane >> 5, o = lane & 31;
    const int lrow = lane & 31;

    int    sv[ET];
    float4 av[ET];
    half8v xh0[ET], xh1[ET];

    #pragma unroll
    for (int r = 0; r < ET; ++r) {
        int er = e0 + 32 * r + lrow;
        int ec = er < E ? er : (E - 1);
        sv[r] = src[ec];
        av[r] = *(const float4*)(ea + 4ll * ec);
    }
    #pragma unroll
    for (int r = 0; r < ET; ++r) {
        if constexpr (INP == 32) {
            const half8v* fp = (const half8v*)(feat + (size_t)sv[r] * 32);
            xh0[r] = fp[g];
            xh1[r] = fp[2 + g];
        } else {
            xh0[r] = *(const half8v*)(feat + (size_t)sv[r] * 8);
        }
    }

    f32x16 C[ET];
    #pragma unroll
    for (int r = 0; r < ET; ++r)
        #pragma unroll
        for (int i = 0; i < 16; ++i) C[r][i] = 0.f;

    const half8v* bp = (const half8v*)bswz;

    if constexpr (INP == 32) {
        #pragma unroll 4
        for (int k = 0; k < 32; ++k) {
            half8v bf0 = bp[(2*k    ) * 64 + lane];
            half8v bf1 = bp[(2*k + 1) * 64 + lane];
            #pragma unroll
            for (int r = 0; r < ET; ++r) {
                float hk = fmaf(av[r].x, w1[k], b1[k]);
                hk = fmaf(av[r].y, w1[32 + k], hk);
                hk = fmaf(av[r].z, w1[64 + k], hk);
                hk = fmaf(av[r].w, w1[96 + k], hk);
                hk = fmaxf(hk, 0.f);
                const _Float16 hh = (_Float16)hk;
                half8v hs;
                #pragma unroll
                for (int j = 0; j < 8; ++j) hs[j] = hh;
                C[r] = __builtin_amdgcn_mfma_f32_32x32x16_f16(hs * xh0[r], bf0, C[r], 0, 0, 0);
                C[r] = __builtin_amdgcn_mfma_f32_32x32x16_f16(hs * xh1[r], bf1, C[r], 0, 0, 0);
            }
        }
        // b2 tail, h == 1: A = raw x fragments
        {
            half8v bf0 = bp[64 * 64 + lane];
            half8v bf1 = bp[65 * 64 + lane];
            #pragma unroll
            for (int r = 0; r < ET; ++r) {
                C[r] = __builtin_amdgcn_mfma_f32_32x32x16_f16(xh0[r], bf0, C[r], 0, 0, 0);
                C[r] = __builtin_amdgcn_mfma_f32_32x32x16_f16(xh1[r], bf1, C[r], 0, 0, 0);
            }
        }
    } else {
        #pragma unroll 4
        for (int t = 0; t < 16; ++t) {
            half8v bf = bp[t * 64 + lane];
            const int k = 2 * t + g;                    // lane-dependent
            #pragma unroll
            for (int r = 0; r < ET; ++r) {
                float hk = fmaf(av[r].x, w1[k], b1[k]);
                hk = fmaf(av[r].y, w1[32 + k], hk);
                hk = fmaf(av[r].z, w1[64 + k], hk);
                hk = fmaf(av[r].w, w1[96 + k], hk);
                hk = fmaxf(hk, 0.f);
                const _Float16 hh = (_Float16)hk;
                half8v hs;
                #pragma unroll
                for (int j = 0; j < 8; ++j) hs[j] = hh;
                C[r] = __builtin_amdgcn_mfma_f32_32x32x16_f16(hs * xh0[r], bf, C[r], 0, 0, 0);
            }
        }
        {
            half8v bf = bp[16 * 64 + lane];             // b2 tail
            half8v zz;
            #pragma unroll
            for (int j = 0; j < 8; ++j) zz[j] = (_Float16)0.f;
            #pragma unroll
            for (int r = 0; r < ET; ++r) {
                half8v a = (g == 0) ? xh0[r] : zz;
                C[r] = __builtin_amdgcn_mfma_f32_32x32x16_f16(a, bf, C[r], 0, 0, 0);
            }
        }
    }

    // epilogue: tile r, reg 4q+m -> edge row e0+32r+8q+4g+m, col o ; f32 atomics
    if (OUT_C == 32 || o < OUT_C) {
        #pragma unroll
        for (int r = 0; r < ET; ++r) {
            const int base = e0 + 32 * r;
            if (base >= E) break;
            #pragma unroll
            for (int q = 0; q < 4; ++q) {
                const int eb = base + 8 * q + 4 * g;
                if (eb + 3 < E) {
                    const int4 dd = *(const int4*)(dst + eb);
                    unsafeAtomicAdd(agg + (size_t)dd.x * OUT_C + o, C[r][4*q + 0]);
                    unsafeAtomicAdd(agg + (size_t)dd.y * OUT_C + o, C[r][4*q + 1]);
                    unsafeAtomicAdd(agg + (size_t)dd.z * OUT_C + o, C[r][4*q + 2]);
                    unsafeAtomicAdd(agg + (size_t)dd.w * OUT_C + o, C[r][4*q + 3]);
                } else {
                    #pragma unroll
                    for (int m = 0; m < 4; ++m)
                        if (eb + m < E)
                            unsafeAtomicAdd(agg + (size_t)dst[eb + m] * OUT_C + o,
                                            C[r][4*q + m]);
                }
            }
        }
    }
}

// ---------------------------------------------------------------------------
// fin: feat = relu(agg) as f16 ; aggN = biasN + relu(agg) @ rootN (f32).
// ---------------------------------------------------------------------------
template<int OUT_NEXT>
__global__ __launch_bounds__(256) void fin(
    const float* __restrict__ agg,    // N x 32
    const float* __restrict__ rootN,  // (32, OUT_NEXT)
    const float* __restrict__ biasN,  // (OUT_NEXT)
    _Float16* __restrict__ feat,      // N x 32 f16
    float* __restrict__ aggN,         // N x OUT_NEXT
    int N)
{
    int v = blockIdx.x * 256 + threadIdx.x;
    if (v >= N) return;

    float f[32];
    const float4* ap = (const float4*)(agg + (size_t)v * 32);
    #pragma unroll
    for (int q = 0; q < 8; ++q) {
        float4 a4 = ap[q];
        f[4*q+0] = fmaxf(a4.x, 0.f);
        f[4*q+1] = fmaxf(a4.y, 0.f);
        f[4*q+2] = fmaxf(a4.z, 0.f);
        f[4*q+3] = fmaxf(a4.w, 0.f);
    }

    half8v* fp = (half8v*)(feat + (size_t)v * 32);
    #pragma unroll
    for (int q = 0; q < 4; ++q) {
        half8v u;
        #pragma unroll
        for (int j = 0; j < 8; ++j) u[j] = (_Float16)f[8*q + j];
        fp[q] = u;
    }

    if constexpr (OUT_NEXT == 32) {
        float4 acc4[8];
        #pragma unroll
        for (int q = 0; q < 8; ++q) {
            #pragma unroll
            for (int m = 0; m < 4; ++m) {
                int o = 4*q + m;
                float a = biasN[o];
                #pragma unroll
                for (int i = 0; i < 32; ++i)
                    a = fmaf(f[i], rootN[i * 32 + o], a);
                ((float*)&acc4[q])[m] = a;
            }
        }
        float4* op = (float4*)(aggN + (size_t)v * 32);
        #pragma unroll
        for (int q = 0; q < 8; ++q) op[q] = acc4[q];
    } else {
        float a0 = biasN[0], a1 = biasN[1];
        #pragma unroll
        for (int i = 0; i < 32; ++i) {
            a0 = fmaf(f[i], rootN[i * 2 + 0], a0);
            a1 = fmaf(f[i], rootN[i * 2 + 1], a1);
        }
        float2 o2; o2.x = a0; o2.y = a1;
        ((float2*)aggN)[v] = o2;
    }
}

// ---------------------------------------------------------------------------
extern "C" void kernel_launch(void* const* d_in, const int* in_sizes, int n_in,
                              void* d_out, int out_size, void* d_ws, size_t ws_size,
                              hipStream_t stream)
{
    const float* x  = (const float*)d_in[0];
    const int*   ei = (const int*)d_in[1];
    const float* ea = (const float*)d_in[2];

    const int E = in_sizes[2] / 4;
    const int N = in_sizes[0] / 10;
    const int* src = ei;
    const int* dst = ei + E;

    const float* p[4][6];   // w1, b1, w2, b2, root, bias
    for (int L = 0; L < 4; ++L)
        for (int j = 0; j < 6; ++j)
            p[L][j] = (const float*)d_in[3 + 6 * L + j];

    char* w = (char*)d_ws;
    auto carve = [&](size_t bytes) {
        char* q = w; w += (bytes + 255) & ~(size_t)255; return (void*)q;
    };
    _Float16* xin  = (_Float16*)carve((size_t)N * 8 * 2);
    _Float16* feat = (_Float16*)carve((size_t)N * 32 * 2);
    float* aggA    = (float*)carve((size_t)N * 32 * 4);
    float* aggB    = (float*)carve((size_t)N * 32 * 4);
    _Float16* bswz = (_Float16*)carve((size_t)BSWZ_TOT * 2);
    float* out     = (float*)d_out;                  // N x 2, init'd by fin<2>

    Prm prm{};
    prm.x = x;
    for (int L = 0; L < 4; ++L) { prm.w2[L] = p[L][2]; prm.b2[L] = p[L][3]; }
    prm.root0 = p[0][4]; prm.bias0 = p[0][5];
    prm.xin = xin; prm.bswz = bswz; prm.agg0 = aggA; prm.N = N;

    const int NB8 = (N * 8 + 255) / 256;             // xin blocks
    const int NBN = (N + 255) / 256;                 // node blocks
    constexpr int ET = 4;                            // edge-tiles per wave
    const int ntile = (E + 32 * ET - 1) / (32 * ET);
    const int ebk   = (ntile + 3) / 4;               // 4 waves / block

    // 8 dispatches total
    prep<<<430 + NB8 + NBN, 256, 0, stream>>>(prm, NB8, NBN);

    edge<8, 32, ET><<<ebk, 256, 0, stream>>>(        // layer 0
        xin, src, dst, ea, p[0][0], p[0][1], bswz + 0, aggA, E);
    fin<32><<<NBN, 256, 0, stream>>>(aggA, p[1][4], p[1][5], feat, aggB, N);

    edge<32, 32, ET><<<ebk, 256, 0, stream>>>(       // layer 1
        feat, src, dst, ea, p[1][0], p[1][1], bswz + 8704, aggB, E);
    fin<32><<<NBN, 256, 0, stream>>>(aggB, p[2][4], p[2][5], feat, aggA, N);

    edge<32, 32, ET><<<ebk, 256, 0, stream>>>(       // layer 2
        feat, src, dst, ea, p[2][0], p[2][1], bswz + 42496, aggA, E);
    fin<2><<<NBN, 256, 0, stream>>>(aggA, p[3][4], p[3][5], feat, out, N);

    edge<32, 2, ET><<<ebk, 256, 0, stream>>>(        // layer 3 -> d_out
        feat, src, dst, ea, p[3][0], p[3][1], bswz + 76288, out, E);
}

// Round 9
// 169.177 us; speedup vs baseline: 1.1635x; 1.1635x over previous
//
#include <hip/hip_runtime.h>
#include <hip/hip_fp16.h>

typedef __attribute__((ext_vector_type(8)))  _Float16 half8v;  // 8 f16 = 4 VGPR
typedef __attribute__((ext_vector_type(16))) float    f32x16;

// bswz step layout (512 f16 per step), offsets in steps:
//  L0 real [0,17)   L0 self [17,19)
//  L1 real [19,85)  L1 self [85,88)
//  L2 real [88,154) L2 self [154,157)
//  L3 real [157,223) L3 self [223,226)
static constexpr int BSWZ_STEPS = 226;
static constexpr int BSWZ_TOT   = BSWZ_STEPS * 512;   // 115712 f16

struct Prm {
    const float* x;
    const float* w2[4]; const float* b2[4];
    const float* root[4]; const float* bias[4];
    _Float16* xin;    // N x 8 f16 (x[:,4:10], zero-padded)
    _Float16* bswz;
    float* aggz;      // 3 * N * 32 f32 (agg0|agg1|agg2), zeroed here
    float* outz;      // N x 2 f32 (d_out), zeroed here
    int N;
};

// ---------------------------------------------------------------------------
// prep: [0,452) build bswz ; [452,452+NB8) pack xin ;
//       [.., +NZA) zero agg0..2 (float4) ; [.., +NZO) zero out (float2).
// ---------------------------------------------------------------------------
__global__ __launch_bounds__(256) void prep(Prm p, int NB8, int NZA, int NZO)
{
    int b = blockIdx.x;
    if (b < 452) {                                   // ---- bswz ----
        int i = b * 256 + threadIdx.x;               // < 115712 exactly
        int T = i >> 9, t2 = i & 511;
        int j = t2 & 7, l = (t2 >> 3) & 63;
        int g = l >> 5, o = l & 31;
        int layer, cls, t;                           // cls: 0 real, 1 self
        if (T < 17)       { layer = 0; cls = 0; t = T; }
        else if (T < 19)  { layer = 0; cls = 1; t = T - 17; }
        else if (T < 85)  { layer = 1; cls = 0; t = T - 19; }
        else if (T < 88)  { layer = 1; cls = 1; t = T - 85; }
        else if (T < 154) { layer = 2; cls = 0; t = T - 88; }
        else if (T < 157) { layer = 2; cls = 1; t = T - 154; }
        else if (T < 223) { layer = 3; cls = 0; t = T - 157; }
        else              { layer = 3; cls = 1; t = T - 223; }
        const int INP   = (layer == 0) ? 8 : 32;
        const int IN_C  = (layer == 0) ? 6 : 32;
        const int OUT_C = (layer == 3) ? 2 : 32;
        float v = 0.f;
        if (cls == 0) {
            const int S_MAIN = 2 * INP;
            if (t < S_MAIN) {
                int kap = 16 * t + 8 * g + j;
                int k  = (INP == 8) ? (kap >> 3) : (kap >> 5);
                int ii = (INP == 8) ? (kap & 7)  : (kap & 31);
                if (ii < IN_C && o < OUT_C)
                    v = p.w2[layer][(size_t)k * (IN_C * OUT_C) + ii * OUT_C + o];
            } else {
                int ii = 16 * (t - S_MAIN) + 8 * g + j;
                if (ii < IN_C && o < OUT_C)
                    v = p.b2[layer][ii * OUT_C + o];
            }
        } else {
            const int nroot = (layer == 0) ? 1 : 2;
            if (t < nroot) {
                int ii = 16 * t + 8 * g + j;
                if (ii < IN_C && o < OUT_C)
                    v = p.root[layer][ii * OUT_C + o];
            } else {
                if (g == 0 && j == 0 && o < OUT_C)
                    v = p.bias[layer][o];
            }
        }
        p.bswz[i] = (_Float16)v;
    } else if (b < 452 + NB8) {                      // ---- pack xin ----
        int i = (b - 452) * 256 + threadIdx.x;
        if (i < p.N * 8) {
            int v = i >> 3, c = i & 7;
            float val = (c < 6) ? p.x[(size_t)v * 10 + 4 + c] : 0.f;
            p.xin[i] = (_Float16)val;
        }
    } else if (b < 452 + NB8 + NZA) {                // ---- zero agg0..2 ----
        long long i = (long long)(b - 452 - NB8) * 256 + threadIdx.x;
        if (i < (long long)p.N * 24)                 // 3*N*32/4 float4
            ((float4*)p.aggz)[i] = float4{0.f, 0.f, 0.f, 0.f};
    } else {                                         // ---- zero out ----
        int v = (b - 452 - NB8 - NZA) * 256 + threadIdx.x;
        if (v < p.N)
            ((float2*)p.outz)[v] = float2{0.f, 0.f};
    }
}

// gather 32 f32 feats for node/src s, relu, cvt to the lane's two f16 octets
static __device__ __forceinline__ void gather32(
    const float* __restrict__ aggPrev, int s, int g, half8v& xh0, half8v& xh1)
{
    const float4* fp = (const float4*)(aggPrev + (size_t)s * 32);
    float4 u0 = fp[2*g], u1 = fp[2*g + 1], u2 = fp[4 + 2*g], u3 = fp[5 + 2*g];
    xh0[0] = (_Float16)fmaxf(u0.x, 0.f); xh0[1] = (_Float16)fmaxf(u0.y, 0.f);
    xh0[2] = (_Float16)fmaxf(u0.z, 0.f); xh0[3] = (_Float16)fmaxf(u0.w, 0.f);
    xh0[4] = (_Float16)fmaxf(u1.x, 0.f); xh0[5] = (_Float16)fmaxf(u1.y, 0.f);
    xh0[6] = (_Float16)fmaxf(u1.z, 0.f); xh0[7] = (_Float16)fmaxf(u1.w, 0.f);
    xh1[0] = (_Float16)fmaxf(u2.x, 0.f); xh1[1] = (_Float16)fmaxf(u2.y, 0.f);
    xh1[2] = (_Float16)fmaxf(u2.z, 0.f); xh1[3] = (_Float16)fmaxf(u2.w, 0.f);
    xh1[4] = (_Float16)fmaxf(u3.x, 0.f); xh1[5] = (_Float16)fmaxf(u3.y, 0.f);
    xh1[6] = (_Float16)fmaxf(u3.z, 0.f); xh1[7] = (_Float16)fmaxf(u3.w, 0.f);
}

// ---------------------------------------------------------------------------
// Edge kernel with fused node-term ("self-edge") tiles.
//  tiles [0, ntileE):      32 real edges — MFMA over K = 32*INP + b2 tail.
//  tiles [ntileE, +ntileN): 32 nodes — 2-3 MFMAs: relu(feat)@root + bias.
// Inter-layer ReLU applied on gather (aggPrev is pre-activation f32).
// C layout: col = lane&31 = o, row = (r&3)+8*(r>>2)+4*(lane>>5).
// Epilogue: f32 atomics into agg (zeroed in prep).
// ---------------------------------------------------------------------------
template<int INP, int OUT_C>
__global__ __launch_bounds__(256) void edge(
    const _Float16* __restrict__ xin,     // layer0 features (N x 8)
    const float*    __restrict__ aggPrev, // mid/final features (N x 32, pre-relu)
    const int*      __restrict__ src,
    const int*      __restrict__ dst,
    const float*    __restrict__ ea,
    const float*    __restrict__ w1,      // (4,32) row-major
    const float*    __restrict__ b1,      // (32)
    const _Float16* __restrict__ bReal,
    const _Float16* __restrict__ bSelf,
    float* __restrict__ agg,              // row stride OUT_C
    int E, int N, int ntileE, int ntot)
{
    const int lane = threadIdx.x & 63;
    const int tile = (blockIdx.x * 256 + threadIdx.x) >> 6;
    if (tile >= ntot) return;
    const int g = lane >> 5, o = lane & 31;
    const int lrow = lane & 31;

    f32x16 C;
    #pragma unroll
    for (int i = 0; i < 16; ++i) C[i] = 0.f;

    half8v ones;
    #pragma unroll
    for (int j = 0; j < 8; ++j) ones[j] = (_Float16)0.f;
    ones[0] = (_Float16)1.f;

    if (tile < ntileE) {
        // ================= real edges =================
        const int e0 = tile * 32;
        const int er = e0 + lrow;
        const int ec = er < E ? er : (E - 1);
        const int s  = src[ec];
        const float4 av = *(const float4*)(ea + 4ll * ec);

        half8v xh0, xh1;
        if constexpr (INP == 32) gather32(aggPrev, s, g, xh0, xh1);
        else                     xh0 = *(const half8v*)(xin + (size_t)s * 8);

        const half8v* bp = (const half8v*)bReal;

        if constexpr (INP == 32) {
            #pragma unroll 4
            for (int k = 0; k < 32; ++k) {
                half8v bf0 = bp[(2*k    ) * 64 + lane];
                half8v bf1 = bp[(2*k + 1) * 64 + lane];
                float hk = fmaf(av.x, w1[k], b1[k]);
                hk = fmaf(av.y, w1[32 + k], hk);
                hk = fmaf(av.z, w1[64 + k], hk);
                hk = fmaf(av.w, w1[96 + k], hk);
                hk = fmaxf(hk, 0.f);
                const _Float16 hh = (_Float16)hk;
                half8v hs;
                #pragma unroll
                for (int j = 0; j < 8; ++j) hs[j] = hh;
                C = __builtin_amdgcn_mfma_f32_32x32x16_f16(hs * xh0, bf0, C, 0, 0, 0);
                C = __builtin_amdgcn_mfma_f32_32x32x16_f16(hs * xh1, bf1, C, 0, 0, 0);
            }
            C = __builtin_amdgcn_mfma_f32_32x32x16_f16(xh0, bp[64*64 + lane], C, 0, 0, 0);
            C = __builtin_amdgcn_mfma_f32_32x32x16_f16(xh1, bp[65*64 + lane], C, 0, 0, 0);
        } else {
            #pragma unroll 4
            for (int t = 0; t < 16; ++t) {
                half8v bf = bp[t * 64 + lane];
                const int k = 2 * t + g;              // lane-dependent
                float hk = fmaf(av.x, w1[k], b1[k]);
                hk = fmaf(av.y, w1[32 + k], hk);
                hk = fmaf(av.z, w1[64 + k], hk);
                hk = fmaf(av.w, w1[96 + k], hk);
                hk = fmaxf(hk, 0.f);
                const _Float16 hh = (_Float16)hk;
                half8v hs;
                #pragma unroll
                for (int j = 0; j < 8; ++j) hs[j] = hh;
                C = __builtin_amdgcn_mfma_f32_32x32x16_f16(hs * xh0, bf, C, 0, 0, 0);
            }
            half8v zz;
            #pragma unroll
            for (int j = 0; j < 8; ++j) zz[j] = (_Float16)0.f;
            half8v a = (g == 0) ? xh0 : zz;           // b2 tail
            C = __builtin_amdgcn_mfma_f32_32x32x16_f16(a, bp[16*64 + lane], C, 0, 0, 0);
        }

        // epilogue: reg 4q+m -> edge row e0+8q+4g+m, col o
        if (OUT_C == 32 || o < OUT_C) {
            #pragma unroll
            for (int q = 0; q < 4; ++q) {
                const int eb = e0 + 8 * q + 4 * g;
                if (eb + 3 < E) {
                    const int4 dd = *(const int4*)(dst + eb);
                    unsafeAtomicAdd(agg + (size_t)dd.x * OUT_C + o, C[4*q + 0]);
                    unsafeAtomicAdd(agg + (size_t)dd.y * OUT_C + o, C[4*q + 1]);
                    unsafeAtomicAdd(agg + (size_t)dd.z * OUT_C + o, C[4*q + 2]);
                    unsafeAtomicAdd(agg + (size_t)dd.w * OUT_C + o, C[4*q + 3]);
                } else {
                    #pragma unroll
                    for (int m = 0; m < 4; ++m)
                        if (eb + m < E)
                            unsafeAtomicAdd(agg + (size_t)dst[eb + m] * OUT_C + o,
                                            C[4*q + m]);
                }
            }
        }
    } else {
        // ================= self edges (node term) =================
        const int v0 = (tile - ntileE) * 32;
        const int vr = v0 + lrow;
        const int vc = vr < N ? vr : (N - 1);

        const half8v* bs = (const half8v*)bSelf;
        if constexpr (INP == 32) {
            half8v xh0, xh1;
            gather32(aggPrev, vc, g, xh0, xh1);
            C = __builtin_amdgcn_mfma_f32_32x32x16_f16(xh0,  bs[0*64 + lane], C, 0, 0, 0);
            C = __builtin_amdgcn_mfma_f32_32x32x16_f16(xh1,  bs[1*64 + lane], C, 0, 0, 0);
            C = __builtin_amdgcn_mfma_f32_32x32x16_f16(ones, bs[2*64 + lane], C, 0, 0, 0);
        } else {
            half8v xh0 = *(const half8v*)(xin + (size_t)vc * 8);
            C = __builtin_amdgcn_mfma_f32_32x32x16_f16(xh0,  bs[0*64 + lane], C, 0, 0, 0);
            C = __builtin_amdgcn_mfma_f32_32x32x16_f16(ones, bs[1*64 + lane], C, 0, 0, 0);
        }

        if (OUT_C == 32 || o < OUT_C) {
            #pragma unroll
            for (int q = 0; q < 4; ++q) {
                #pragma unroll
                for (int m = 0; m < 4; ++m) {
                    const int row = v0 + 8*q + 4*g + m;
                    if (row < N)
                        unsafeAtomicAdd(agg + (size_t)row * OUT_C + o, C[4*q + m]);
                }
            }
        }
    }
}

// ---------------------------------------------------------------------------
extern "C" void kernel_launch(void* const* d_in, const int* in_sizes, int n_in,
                              void* d_out, int out_size, void* d_ws, size_t ws_size,
                              hipStream_t stream)
{
    const float* x  = (const float*)d_in[0];
    const int*   ei = (const int*)d_in[1];
    const float* ea = (const float*)d_in[2];

    const int E = in_sizes[2] / 4;
    const int N = in_sizes[0] / 10;
    const int* src = ei;
    const int* dst = ei + E;

    const float* p[4][6];   // w1, b1, w2, b2, root, bias
    for (int L = 0; L < 4; ++L)
        for (int j = 0; j < 6; ++j)
            p[L][j] = (const float*)d_in[3 + 6 * L + j];

    char* w = (char*)d_ws;
    auto carve = [&](size_t bytes) {
        char* q = w; w += (bytes + 255) & ~(size_t)255; return (void*)q;
    };
    _Float16* xin   = (_Float16*)carve((size_t)N * 8 * 2);
    float*    aggz  = (float*)carve((size_t)3 * N * 32 * 4);  // agg0|agg1|agg2
    _Float16* bswz  = (_Float16*)carve((size_t)BSWZ_TOT * 2);
    float* agg0 = aggz;
    float* agg1 = aggz + (size_t)N * 32;
    float* agg2 = aggz + (size_t)2 * N * 32;
    float* out  = (float*)d_out;

    Prm prm{};
    prm.x = x;
    for (int L = 0; L < 4; ++L) {
        prm.w2[L] = p[L][2]; prm.b2[L] = p[L][3];
        prm.root[L] = p[L][4]; prm.bias[L] = p[L][5];
    }
    prm.xin = xin; prm.bswz = bswz; prm.aggz = aggz; prm.outz = out; prm.N = N;

    const int NB8 = (N * 8 + 255) / 256;
    const int NZA = (N * 24 + 255) / 256;            // 3*N*32/4 float4
    const int NZO = (N + 255) / 256;                 // N float2

    const int ntileE = (E + 31) / 32;
    const int ntileN = (N + 31) / 32;
    const int ntot   = ntileE + ntileN;
    const int ebk    = (ntot + 3) / 4;               // 4 wave-tiles / block

    // 5 dispatches total
    prep<<<452 + NB8 + NZA + NZO, 256, 0, stream>>>(prm, NB8, NZA, NZO);

    edge<8, 32><<<ebk, 256, 0, stream>>>(            // layer 0
        xin, nullptr, src, dst, ea, p[0][0], p[0][1],
        bswz + 0 * 512, bswz + 17 * 512, agg0, E, N, ntileE, ntot);

    edge<32, 32><<<ebk, 256, 0, stream>>>(           // layer 1
        nullptr, agg0, src, dst, ea, p[1][0], p[1][1],
        bswz + 19 * 512, bswz + 85 * 512, agg1, E, N, ntileE, ntot);

    edge<32, 32><<<ebk, 256, 0, stream>>>(           // layer 2
        nullptr, agg1, src, dst, ea, p[2][0], p[2][1],
        bswz + 88 * 512, bswz + 154 * 512, agg2, E, N, ntileE, ntot);

    edge<32, 2><<<ebk, 256, 0, stream>>>(            // layer 3 -> d_out
        nullptr, agg2, src, dst, ea, p[3][0], p[3][1],
        bswz + 157 * 512, bswz + 223 * 512, out, E, N, ntileE, ntot);
}

// Round 10
// 161.872 us; speedup vs baseline: 1.2160x; 1.0451x over previous
//
#include <hip/hip_runtime.h>
#include <hip/hip_fp16.h>

typedef __attribute__((ext_vector_type(8)))  _Float16 half8v;  // 8 f16 = 4 VGPR
typedef __attribute__((ext_vector_type(16))) float    f32x16;

// bswz step layout (512 f16 per step), offsets in steps:
//  L0 real [0,17)   L0 self [17,19)
//  L1 real [19,85)  L1 self [85,88)
//  L2 real [88,154) L2 self [154,157)
//  L3 real [157,223) L3 self [223,226)
static constexpr int BSWZ_STEPS = 226;
static constexpr int BSWZ_TOT   = BSWZ_STEPS * 512;   // 115712 f16

struct Prm {
    const float* x;
    const float* w2[4]; const float* b2[4];
    const float* root[4]; const float* bias[4];
    _Float16* xin;    // N x 8 f16 (x[:,4:10], zero-padded)
    _Float16* bswz;
    float* aggz;      // 3 * N * 32 f32 (agg0|agg1|agg2), zeroed here
    float* outz;      // N x 2 f32 (d_out), zeroed here
    int N;
};

// ---------------------------------------------------------------------------
// prep: [0,452) build bswz ; [452,452+NB8) pack xin ;
//       [.., +NZA) zero agg0..2 (float4) ; [.., +NZO) zero out (float2).
// ---------------------------------------------------------------------------
__global__ __launch_bounds__(256) void prep(Prm p, int NB8, int NZA, int NZO)
{
    int b = blockIdx.x;
    if (b < 452) {                                   // ---- bswz ----
        int i = b * 256 + threadIdx.x;               // < 115712 exactly
        int T = i >> 9, t2 = i & 511;
        int j = t2 & 7, l = (t2 >> 3) & 63;
        int g = l >> 5, o = l & 31;
        int layer, cls, t;                           // cls: 0 real, 1 self
        if (T < 17)       { layer = 0; cls = 0; t = T; }
        else if (T < 19)  { layer = 0; cls = 1; t = T - 17; }
        else if (T < 85)  { layer = 1; cls = 0; t = T - 19; }
        else if (T < 88)  { layer = 1; cls = 1; t = T - 85; }
        else if (T < 154) { layer = 2; cls = 0; t = T - 88; }
        else if (T < 157) { layer = 2; cls = 1; t = T - 154; }
        else if (T < 223) { layer = 3; cls = 0; t = T - 157; }
        else              { layer = 3; cls = 1; t = T - 223; }
        const int INP   = (layer == 0) ? 8 : 32;
        const int IN_C  = (layer == 0) ? 6 : 32;
        const int OUT_C = (layer == 3) ? 2 : 32;
        float v = 0.f;
        if (cls == 0) {
            const int S_MAIN = 2 * INP;
            if (t < S_MAIN) {
                int kap = 16 * t + 8 * g + j;
                int k  = (INP == 8) ? (kap >> 3) : (kap >> 5);
                int ii = (INP == 8) ? (kap & 7)  : (kap & 31);
                if (ii < IN_C && o < OUT_C)
                    v = p.w2[layer][(size_t)k * (IN_C * OUT_C) + ii * OUT_C + o];
            } else {
                int ii = 16 * (t - S_MAIN) + 8 * g + j;
                if (ii < IN_C && o < OUT_C)
                    v = p.b2[layer][ii * OUT_C + o];
            }
        } else {
            const int nroot = (layer == 0) ? 1 : 2;
            if (t < nroot) {
                int ii = 16 * t + 8 * g + j;
                if (ii < IN_C && o < OUT_C)
                    v = p.root[layer][ii * OUT_C + o];
            } else {
                if (g == 0 && j == 0 && o < OUT_C)
                    v = p.bias[layer][o];
            }
        }
        p.bswz[i] = (_Float16)v;
    } else if (b < 452 + NB8) {                      // ---- pack xin ----
        int i = (b - 452) * 256 + threadIdx.x;
        if (i < p.N * 8) {
            int v = i >> 3, c = i & 7;
            float val = (c < 6) ? p.x[(size_t)v * 10 + 4 + c] : 0.f;
            p.xin[i] = (_Float16)val;
        }
    } else if (b < 452 + NB8 + NZA) {                // ---- zero agg0..2 ----
        long long i = (long long)(b - 452 - NB8) * 256 + threadIdx.x;
        if (i < (long long)p.N * 24)                 // 3*N*32/4 float4
            ((float4*)p.aggz)[i] = float4{0.f, 0.f, 0.f, 0.f};
    } else {                                         // ---- zero out ----
        int v = (b - 452 - NB8 - NZA) * 256 + threadIdx.x;
        if (v < p.N)
            ((float2*)p.outz)[v] = float2{0.f, 0.f};
    }
}

// gather 32 f32 feats for node/src s, relu, cvt to the lane's two f16 octets
static __device__ __forceinline__ void gather32(
    const float* __restrict__ aggPrev, int s, int g, half8v& xh0, half8v& xh1)
{
    const float4* fp = (const float4*)(aggPrev + (size_t)s * 32);
    float4 u0 = fp[2*g], u1 = fp[2*g + 1], u2 = fp[4 + 2*g], u3 = fp[5 + 2*g];
    xh0[0] = (_Float16)fmaxf(u0.x, 0.f); xh0[1] = (_Float16)fmaxf(u0.y, 0.f);
    xh0[2] = (_Float16)fmaxf(u0.z, 0.f); xh0[3] = (_Float16)fmaxf(u0.w, 0.f);
    xh0[4] = (_Float16)fmaxf(u1.x, 0.f); xh0[5] = (_Float16)fmaxf(u1.y, 0.f);
    xh0[6] = (_Float16)fmaxf(u1.z, 0.f); xh0[7] = (_Float16)fmaxf(u1.w, 0.f);
    xh1[0] = (_Float16)fmaxf(u2.x, 0.f); xh1[1] = (_Float16)fmaxf(u2.y, 0.f);
    xh1[2] = (_Float16)fmaxf(u2.z, 0.f); xh1[3] = (_Float16)fmaxf(u2.w, 0.f);
    xh1[4] = (_Float16)fmaxf(u3.x, 0.f); xh1[5] = (_Float16)fmaxf(u3.y, 0.f);
    xh1[6] = (_Float16)fmaxf(u3.z, 0.f); xh1[7] = (_Float16)fmaxf(u3.w, 0.f);
}

// ---------------------------------------------------------------------------
// Edge kernel, LDS-staged B fragments.  Block = 512 threads stages the whole
// layer's fragment sequence (real + self, <=70.7 KB) into LDS once, then its
// 8 waves grid-stride over tiles:
//  tiles [0, ntileE):      32 real edges — MFMA over K = 32*INP + b2 tail
//  tiles [ntileE, ntot):   32 nodes     — 2-3 MFMAs (root term + bias)
// ds_read_b128 of a contiguous 1KB slab per step: conflict-free, ~12cyc tput
// (vs ~200cyc L2 round-trip per fragment in R9: the 11%-MfmaUtil stall).
// C layout: col = lane&31 = o, row = (r&3)+8*(r>>2)+4*(lane>>5).
// ---------------------------------------------------------------------------
template<int INP, int OUT_C>
__global__ __launch_bounds__(512) void edge(
    const _Float16* __restrict__ xin,     // layer0 features (N x 8)
    const float*    __restrict__ aggPrev, // mid/final features (N x 32, pre-relu)
    const int*      __restrict__ src,
    const int*      __restrict__ dst,
    const float*    __restrict__ ea,
    const float*    __restrict__ w1,      // (4,32) row-major
    const float*    __restrict__ b1,      // (32)
    const _Float16* __restrict__ bAll,    // real || self fragments, contiguous
    float* __restrict__ agg,              // row stride OUT_C
    int E, int N, int ntileE, int ntot)
{
    constexpr int NREAL = (INP == 32) ? 66 : 17;
    constexpr int NSELF = (INP == 32) ? 3  : 2;
    constexpr int NSTEP = NREAL + NSELF;

    __shared__ half8v ldsb[NSTEP * 64];
    {
        const half8v* bp = (const half8v*)bAll;
        for (int i = threadIdx.x; i < NSTEP * 64; i += 512)
            ldsb[i] = bp[i];
    }
    __syncthreads();

    const int lane = threadIdx.x & 63;
    const int g = lane >> 5, o = lane & 31;
    const int lrow = lane & 31;
    const int wv = (blockIdx.x * 512 + threadIdx.x) >> 6;
    const int nw = gridDim.x * 8;

    half8v ones;
    #pragma unroll
    for (int j = 0; j < 8; ++j) ones[j] = (_Float16)0.f;
    ones[0] = (_Float16)1.f;

    for (int tile = wv; tile < ntot; tile += nw) {
        f32x16 C;
        #pragma unroll
        for (int i = 0; i < 16; ++i) C[i] = 0.f;

        if (tile < ntileE) {
            // ================= real edges =================
            const int e0 = tile * 32;
            const int er = e0 + lrow;
            const int ec = er < E ? er : (E - 1);
            const int s  = src[ec];
            const float4 av = *(const float4*)(ea + 4ll * ec);

            half8v xh0, xh1;
            if constexpr (INP == 32) gather32(aggPrev, s, g, xh0, xh1);
            else                     xh0 = *(const half8v*)(xin + (size_t)s * 8);

            if constexpr (INP == 32) {
                #pragma unroll 4
                for (int k = 0; k < 32; ++k) {
                    half8v bf0 = ldsb[(2*k    ) * 64 + lane];
                    half8v bf1 = ldsb[(2*k + 1) * 64 + lane];
                    float hk = fmaf(av.x, w1[k], b1[k]);
                    hk = fmaf(av.y, w1[32 + k], hk);
                    hk = fmaf(av.z, w1[64 + k], hk);
                    hk = fmaf(av.w, w1[96 + k], hk);
                    hk = fmaxf(hk, 0.f);
                    const _Float16 hh = (_Float16)hk;
                    half8v hs;
                    #pragma unroll
                    for (int j = 0; j < 8; ++j) hs[j] = hh;
                    C = __builtin_amdgcn_mfma_f32_32x32x16_f16(hs * xh0, bf0, C, 0, 0, 0);
                    C = __builtin_amdgcn_mfma_f32_32x32x16_f16(hs * xh1, bf1, C, 0, 0, 0);
                }
                C = __builtin_amdgcn_mfma_f32_32x32x16_f16(xh0, ldsb[64*64 + lane], C, 0, 0, 0);
                C = __builtin_amdgcn_mfma_f32_32x32x16_f16(xh1, ldsb[65*64 + lane], C, 0, 0, 0);
            } else {
                #pragma unroll 4
                for (int t = 0; t < 16; ++t) {
                    half8v bf = ldsb[t * 64 + lane];
                    const int k = 2 * t + g;              // lane-dependent
                    float hk = fmaf(av.x, w1[k], b1[k]);
                    hk = fmaf(av.y, w1[32 + k], hk);
                    hk = fmaf(av.z, w1[64 + k], hk);
                    hk = fmaf(av.w, w1[96 + k], hk);
                    hk = fmaxf(hk, 0.f);
                    const _Float16 hh = (_Float16)hk;
                    half8v hs;
                    #pragma unroll
                    for (int j = 0; j < 8; ++j) hs[j] = hh;
                    C = __builtin_amdgcn_mfma_f32_32x32x16_f16(hs * xh0, bf, C, 0, 0, 0);
                }
                half8v zz;
                #pragma unroll
                for (int j = 0; j < 8; ++j) zz[j] = (_Float16)0.f;
                half8v a = (g == 0) ? xh0 : zz;           // b2 tail
                C = __builtin_amdgcn_mfma_f32_32x32x16_f16(a, ldsb[16*64 + lane], C, 0, 0, 0);
            }

            // epilogue: reg 4q+m -> edge row e0+8q+4g+m, col o
            if (OUT_C == 32 || o < OUT_C) {
                #pragma unroll
                for (int q = 0; q < 4; ++q) {
                    const int eb = e0 + 8 * q + 4 * g;
                    if (eb + 3 < E) {
                        const int4 dd = *(const int4*)(dst + eb);
                        unsafeAtomicAdd(agg + (size_t)dd.x * OUT_C + o, C[4*q + 0]);
                        unsafeAtomicAdd(agg + (size_t)dd.y * OUT_C + o, C[4*q + 1]);
                        unsafeAtomicAdd(agg + (size_t)dd.z * OUT_C + o, C[4*q + 2]);
                        unsafeAtomicAdd(agg + (size_t)dd.w * OUT_C + o, C[4*q + 3]);
                    } else {
                        #pragma unroll
                        for (int m = 0; m < 4; ++m)
                            if (eb + m < E)
                                unsafeAtomicAdd(agg + (size_t)dst[eb + m] * OUT_C + o,
                                                C[4*q + m]);
                    }
                }
            }
        } else {
            // ================= self edges (node term) =================
            const int v0 = (tile - ntileE) * 32;
            const int vr = v0 + lrow;
            const int vc = vr < N ? vr : (N - 1);

            if constexpr (INP == 32) {
                half8v xh0, xh1;
                gather32(aggPrev, vc, g, xh0, xh1);
                C = __builtin_amdgcn_mfma_f32_32x32x16_f16(xh0,  ldsb[(NREAL+0)*64 + lane], C, 0, 0, 0);
                C = __builtin_amdgcn_mfma_f32_32x32x16_f16(xh1,  ldsb[(NREAL+1)*64 + lane], C, 0, 0, 0);
                C = __builtin_amdgcn_mfma_f32_32x32x16_f16(ones, ldsb[(NREAL+2)*64 + lane], C, 0, 0, 0);
            } else {
                half8v xh0 = *(const half8v*)(xin + (size_t)vc * 8);
                C = __builtin_amdgcn_mfma_f32_32x32x16_f16(xh0,  ldsb[(NREAL+0)*64 + lane], C, 0, 0, 0);
                C = __builtin_amdgcn_mfma_f32_32x32x16_f16(ones, ldsb[(NREAL+1)*64 + lane], C, 0, 0, 0);
            }

            if (OUT_C == 32 || o < OUT_C) {
                #pragma unroll
                for (int q = 0; q < 4; ++q) {
                    #pragma unroll
                    for (int m = 0; m < 4; ++m) {
                        const int row = v0 + 8*q + 4*g + m;
                        if (row < N)
                            unsafeAtomicAdd(agg + (size_t)row * OUT_C + o, C[4*q + m]);
                    }
                }
            }
        }
    }
}

// ---------------------------------------------------------------------------
extern "C" void kernel_launch(void* const* d_in, const int* in_sizes, int n_in,
                              void* d_out, int out_size, void* d_ws, size_t ws_size,
                              hipStream_t stream)
{
    const float* x  = (const float*)d_in[0];
    const int*   ei = (const int*)d_in[1];
    const float* ea = (const float*)d_in[2];

    const int E = in_sizes[2] / 4;
    const int N = in_sizes[0] / 10;
    const int* src = ei;
    const int* dst = ei + E;

    const float* p[4][6];   // w1, b1, w2, b2, root, bias
    for (int L = 0; L < 4; ++L)
        for (int j = 0; j < 6; ++j)
            p[L][j] = (const float*)d_in[3 + 6 * L + j];

    char* w = (char*)d_ws;
    auto carve = [&](size_t bytes) {
        char* q = w; w += (bytes + 255) & ~(size_t)255; return (void*)q;
    };
    _Float16* xin   = (_Float16*)carve((size_t)N * 8 * 2);
    float*    aggz  = (float*)carve((size_t)3 * N * 32 * 4);  // agg0|agg1|agg2
    _Float16* bswz  = (_Float16*)carve((size_t)BSWZ_TOT * 2);
    float* agg0 = aggz;
    float* agg1 = aggz + (size_t)N * 32;
    float* agg2 = aggz + (size_t)2 * N * 32;
    float* out  = (float*)d_out;

    Prm prm{};
    prm.x = x;
    for (int L = 0; L < 4; ++L) {
        prm.w2[L] = p[L][2]; prm.b2[L] = p[L][3];
        prm.root[L] = p[L][4]; prm.bias[L] = p[L][5];
    }
    prm.xin = xin; prm.bswz = bswz; prm.aggz = aggz; prm.outz = out; prm.N = N;

    const int NB8 = (N * 8 + 255) / 256;
    const int NZA = (N * 24 + 255) / 256;            // 3*N*32/4 float4
    const int NZO = (N + 255) / 256;                 // N float2

    const int ntileE = (E + 31) / 32;
    const int ntileN = (N + 31) / 32;
    const int ntot   = ntileE + ntileN;
    int NB = (ntot + 7) / 8;                         // 8 waves / block
    if (NB > 512) NB = 512;                          // 2 blocks/CU co-resident

    // 5 dispatches total
    prep<<<452 + NB8 + NZA + NZO, 256, 0, stream>>>(prm, NB8, NZA, NZO);

    edge<8, 32><<<NB, 512, 0, stream>>>(             // layer 0
        xin, nullptr, src, dst, ea, p[0][0], p[0][1],
        bswz + 0 * 512, agg0, E, N, ntileE, ntot);

    edge<32, 32><<<NB, 512, 0, stream>>>(            // layer 1
        nullptr, agg0, src, dst, ea, p[1][0], p[1][1],
        bswz + 19 * 512, agg1, E, N, ntileE, ntot);

    edge<32, 32><<<NB, 512, 0, stream>>>(            // layer 2
        nullptr, agg1, src, dst, ea, p[2][0], p[2][1],
        bswz + 88 * 512, agg2, E, N, ntileE, ntot);

    edge<32, 2><<<NB, 512, 0, stream>>>(             // layer 3 -> d_out
        nullptr, agg2, src, dst, ea, p[3][0], p[3][1],
        bswz + 157 * 512, out, E, N, ntileE, ntot);
}

// Round 11
// 126.630 us; speedup vs baseline: 1.5544x; 1.2783x over previous
//
#include <hip/hip_runtime.h>
#include <hip/hip_fp16.h>

typedef __attribute__((ext_vector_type(8)))  _Float16 half8v;  // 8 f16 = 4 VGPR
typedef __attribute__((ext_vector_type(16))) float    f32x16;

// bswz step layout (512 f16 per step), offsets in steps:
//  L0 real [0,17)   L0 self [17,19)
//  L1 real [19,85)  L1 self [85,88)
//  L2 real [88,154) L2 self [154,157)
//  L3 real [157,223) L3 self [223,226)
static constexpr int BSWZ_STEPS = 226;
static constexpr int BSWZ_TOT   = BSWZ_STEPS * 512;   // 115712 f16

struct Prm {
    const float* x;
    const float* w2[4]; const float* b2[4];
    const float* root[4]; const float* bias[4];
    _Float16* xin;    // N x 8 f16 (x[:,4:10], zero-padded)
    _Float16* bswz;
    _Float16* aggz;   // 3 * N * 32 f16 (agg0|agg1|agg2), zeroed here
    float* outz;      // N x 2 f32 (d_out), zeroed here
    int N;
};

// ---------------------------------------------------------------------------
// prep: [0,452) build bswz ; [452,452+NB8) pack xin ;
//       [.., +NZA) zero agg0..2 (uint4) ; [.., +NZO) zero out (float2).
// ---------------------------------------------------------------------------
__global__ __launch_bounds__(256) void prep(Prm p, int NB8, int NZA, int NZO)
{
    int b = blockIdx.x;
    if (b < 452) {                                   // ---- bswz ----
        int i = b * 256 + threadIdx.x;               // < 115712 exactly
        int T = i >> 9, t2 = i & 511;
        int j = t2 & 7, l = (t2 >> 3) & 63;
        int g = l >> 5, o = l & 31;
        int layer, cls, t;                           // cls: 0 real, 1 self
        if (T < 17)       { layer = 0; cls = 0; t = T; }
        else if (T < 19)  { layer = 0; cls = 1; t = T - 17; }
        else if (T < 85)  { layer = 1; cls = 0; t = T - 19; }
        else if (T < 88)  { layer = 1; cls = 1; t = T - 85; }
        else if (T < 154) { layer = 2; cls = 0; t = T - 88; }
        else if (T < 157) { layer = 2; cls = 1; t = T - 154; }
        else if (T < 223) { layer = 3; cls = 0; t = T - 157; }
        else              { layer = 3; cls = 1; t = T - 223; }
        const int INP   = (layer == 0) ? 8 : 32;
        const int IN_C  = (layer == 0) ? 6 : 32;
        const int OUT_C = (layer == 3) ? 2 : 32;
        float v = 0.f;
        if (cls == 0) {
            const int S_MAIN = 2 * INP;
            if (t < S_MAIN) {
                int kap = 16 * t + 8 * g + j;
                int k  = (INP == 8) ? (kap >> 3) : (kap >> 5);
                int ii = (INP == 8) ? (kap & 7)  : (kap & 31);
                if (ii < IN_C && o < OUT_C)
                    v = p.w2[layer][(size_t)k * (IN_C * OUT_C) + ii * OUT_C + o];
            } else {
                int ii = 16 * (t - S_MAIN) + 8 * g + j;
                if (ii < IN_C && o < OUT_C)
                    v = p.b2[layer][ii * OUT_C + o];
            }
        } else {
            const int nroot = (layer == 0) ? 1 : 2;
            if (t < nroot) {
                int ii = 16 * t + 8 * g + j;
                if (ii < IN_C && o < OUT_C)
                    v = p.root[layer][ii * OUT_C + o];
            } else {
                if (g == 0 && j == 0 && o < OUT_C)
                    v = p.bias[layer][o];
            }
        }
        p.bswz[i] = (_Float16)v;
    } else if (b < 452 + NB8) {                      // ---- pack xin ----
        int i = (b - 452) * 256 + threadIdx.x;
        if (i < p.N * 8) {
            int v = i >> 3, c = i & 7;
            float val = (c < 6) ? p.x[(size_t)v * 10 + 4 + c] : 0.f;
            p.xin[i] = (_Float16)val;
        }
    } else if (b < 452 + NB8 + NZA) {                // ---- zero agg0..2 ----
        long long i = (long long)(b - 452 - NB8) * 256 + threadIdx.x;
        if (i < (long long)p.N * 12)                 // 3*N*32*2B / 16B
            ((uint4*)p.aggz)[i] = uint4{0u, 0u, 0u, 0u};
    } else {                                         // ---- zero out ----
        int v = (b - 452 - NB8 - NZA) * 256 + threadIdx.x;
        if (v < p.N)
            ((float2*)p.outz)[v] = float2{0.f, 0.f};
    }
}

// gather 32 f16 feats for node s, relu in packed f16 (no cvt needed)
static __device__ __forceinline__ void gather32h(
    const _Float16* __restrict__ fprev, int s, int g, half8v& xh0, half8v& xh1)
{
    const half8v* fp = (const half8v*)(fprev + (size_t)s * 32);
    xh0 = fp[g];
    xh1 = fp[2 + g];
    #pragma unroll
    for (int j = 0; j < 8; ++j) {
        xh0[j] = xh0[j] > (_Float16)0.f ? xh0[j] : (_Float16)0.f;
        xh1[j] = xh1[j] > (_Float16)0.f ? xh1[j] : (_Float16)0.f;
    }
}

// paired pk-f16 atomic: lane o and o^1 hold the same row, cols o / o^1.
// Even lane packs (mine, other) and issues ONE global_atomic_pk_add_f16.
static __device__ __forceinline__ void pk_atomic_row(
    _Float16* __restrict__ aggH, int row, int o, float mine)
{
    float oth = __shfl_xor(mine, 1);
    if ((o & 1) == 0 && row >= 0) {
        __half2 v = __floats2half2_rn(mine, oth);
        unsafeAtomicAdd((__half2*)aggH + (((size_t)row << 5) + o) / 2, v);
    }
}

// ---------------------------------------------------------------------------
// Edge kernel, LDS-staged B fragments, pk-f16 atomic aggregation.
//  tiles [0, ntileE):    32 real edges — MFMA over K = 32*INP + b2 tail
//  tiles [ntileE, ntot): 32 nodes     — 2-3 MFMAs (root term + bias)
// C layout: col = lane&31 = o, row = (r&3)+8*(r>>2)+4*(lane>>5).
// OUT_C==32: agg is f16 (pk atomics).  OUT_C==2: agg is f32 d_out.
// ---------------------------------------------------------------------------
template<int INP, int OUT_C>
__global__ __launch_bounds__(512) void edge(
    const _Float16* __restrict__ xin,     // layer0 features (N x 8)
    const _Float16* __restrict__ fprev,   // mid/final features (N x 32 f16, pre-relu)
    const int*      __restrict__ src,
    const int*      __restrict__ dst,
    const float*    __restrict__ ea,
    const float*    __restrict__ w1,      // (4,32) row-major
    const float*    __restrict__ b1,      // (32)
    const _Float16* __restrict__ bAll,    // real || self fragments, contiguous
    _Float16* __restrict__ aggH,          // N x 32 f16 (OUT_C==32)
    float*    __restrict__ aggF,          // N x 2 f32  (OUT_C==2)
    int E, int N, int ntileE, int ntot)
{
    constexpr int NREAL = (INP == 32) ? 66 : 17;
    constexpr int NSELF = (INP == 32) ? 3  : 2;
    constexpr int NSTEP = NREAL + NSELF;

    __shared__ half8v ldsb[NSTEP * 64];
    {
        const half8v* bp = (const half8v*)bAll;
        for (int i = threadIdx.x; i < NSTEP * 64; i += 512)
            ldsb[i] = bp[i];
    }
    __syncthreads();

    const int lane = threadIdx.x & 63;
    const int g = lane >> 5, o = lane & 31;
    const int lrow = lane & 31;
    const int wv = (blockIdx.x * 512 + threadIdx.x) >> 6;
    const int nw = gridDim.x * 8;

    half8v ones;
    #pragma unroll
    for (int j = 0; j < 8; ++j) ones[j] = (_Float16)0.f;
    ones[0] = (_Float16)1.f;

    for (int tile = wv; tile < ntot; tile += nw) {
        f32x16 C;
        #pragma unroll
        for (int i = 0; i < 16; ++i) C[i] = 0.f;

        if (tile < ntileE) {
            // ================= real edges =================
            const int e0 = tile * 32;
            const int er = e0 + lrow;
            const int ec = er < E ? er : (E - 1);
            const int s  = src[ec];
            const float4 av = *(const float4*)(ea + 4ll * ec);

            half8v xh0, xh1;
            if constexpr (INP == 32) gather32h(fprev, s, g, xh0, xh1);
            else                     xh0 = *(const half8v*)(xin + (size_t)s * 8);

            if constexpr (INP == 32) {
                #pragma unroll 4
                for (int k = 0; k < 32; ++k) {
                    half8v bf0 = ldsb[(2*k    ) * 64 + lane];
                    half8v bf1 = ldsb[(2*k + 1) * 64 + lane];
                    float hk = fmaf(av.x, w1[k], b1[k]);
                    hk = fmaf(av.y, w1[32 + k], hk);
                    hk = fmaf(av.z, w1[64 + k], hk);
                    hk = fmaf(av.w, w1[96 + k], hk);
                    hk = fmaxf(hk, 0.f);
                    const _Float16 hh = (_Float16)hk;
                    half8v hs;
                    #pragma unroll
                    for (int j = 0; j < 8; ++j) hs[j] = hh;
                    C = __builtin_amdgcn_mfma_f32_32x32x16_f16(hs * xh0, bf0, C, 0, 0, 0);
                    C = __builtin_amdgcn_mfma_f32_32x32x16_f16(hs * xh1, bf1, C, 0, 0, 0);
                }
                C = __builtin_amdgcn_mfma_f32_32x32x16_f16(xh0, ldsb[64*64 + lane], C, 0, 0, 0);
                C = __builtin_amdgcn_mfma_f32_32x32x16_f16(xh1, ldsb[65*64 + lane], C, 0, 0, 0);
            } else {
                #pragma unroll 4
                for (int t = 0; t < 16; ++t) {
                    half8v bf = ldsb[t * 64 + lane];
                    const int k = 2 * t + g;              // lane-dependent
                    float hk = fmaf(av.x, w1[k], b1[k]);
                    hk = fmaf(av.y, w1[32 + k], hk);
                    hk = fmaf(av.z, w1[64 + k], hk);
                    hk = fmaf(av.w, w1[96 + k], hk);
                    hk = fmaxf(hk, 0.f);
                    const _Float16 hh = (_Float16)hk;
                    half8v hs;
                    #pragma unroll
                    for (int j = 0; j < 8; ++j) hs[j] = hh;
                    C = __builtin_amdgcn_mfma_f32_32x32x16_f16(hs * xh0, bf, C, 0, 0, 0);
                }
                half8v zz;
                #pragma unroll
                for (int j = 0; j < 8; ++j) zz[j] = (_Float16)0.f;
                half8v a = (g == 0) ? xh0 : zz;           // b2 tail
                C = __builtin_amdgcn_mfma_f32_32x32x16_f16(a, ldsb[16*64 + lane], C, 0, 0, 0);
            }

            // epilogue: reg 4q+m -> edge row e0+8q+4g+m, col o
            if constexpr (OUT_C == 32) {
                #pragma unroll
                for (int q = 0; q < 4; ++q) {
                    const int eb = e0 + 8 * q + 4 * g;
                    int rows[4];
                    if (eb + 3 < E) {
                        const int4 dd = *(const int4*)(dst + eb);
                        rows[0] = dd.x; rows[1] = dd.y; rows[2] = dd.z; rows[3] = dd.w;
                    } else {
                        #pragma unroll
                        for (int m = 0; m < 4; ++m)
                            rows[m] = (eb + m < E) ? dst[eb + m] : -1;
                    }
                    #pragma unroll
                    for (int m = 0; m < 4; ++m)
                        pk_atomic_row(aggH, rows[m], o, C[4*q + m]);
                }
            } else {
                if (o < OUT_C) {
                    #pragma unroll
                    for (int q = 0; q < 4; ++q) {
                        const int eb = e0 + 8 * q + 4 * g;
                        #pragma unroll
                        for (int m = 0; m < 4; ++m)
                            if (eb + m < E)
                                unsafeAtomicAdd(aggF + (size_t)dst[eb + m] * OUT_C + o,
                                                C[4*q + m]);
                    }
                }
            }
        } else {
            // ================= self edges (node term) =================
            const int v0 = (tile - ntileE) * 32;
            const int vr = v0 + lrow;
            const int vc = vr < N ? vr : (N - 1);

            if constexpr (INP == 32) {
                half8v xh0, xh1;
                gather32h(fprev, vc, g, xh0, xh1);
                C = __builtin_amdgcn_mfma_f32_32x32x16_f16(xh0,  ldsb[(NREAL+0)*64 + lane], C, 0, 0, 0);
                C = __builtin_amdgcn_mfma_f32_32x32x16_f16(xh1,  ldsb[(NREAL+1)*64 + lane], C, 0, 0, 0);
                C = __builtin_amdgcn_mfma_f32_32x32x16_f16(ones, ldsb[(NREAL+2)*64 + lane], C, 0, 0, 0);
            } else {
                half8v xh0 = *(const half8v*)(xin + (size_t)vc * 8);
                C = __builtin_amdgcn_mfma_f32_32x32x16_f16(xh0,  ldsb[(NREAL+0)*64 + lane], C, 0, 0, 0);
                C = __builtin_amdgcn_mfma_f32_32x32x16_f16(ones, ldsb[(NREAL+1)*64 + lane], C, 0, 0, 0);
            }

            if constexpr (OUT_C == 32) {
                #pragma unroll
                for (int q = 0; q < 4; ++q) {
                    #pragma unroll
                    for (int m = 0; m < 4; ++m) {
                        const int row = v0 + 8*q + 4*g + m;
                        pk_atomic_row(aggH, row < N ? row : -1, o, C[4*q + m]);
                    }
                }
            } else {
                if (o < OUT_C) {
                    #pragma unroll
                    for (int q = 0; q < 4; ++q) {
                        #pragma unroll
                        for (int m = 0; m < 4; ++m) {
                            const int row = v0 + 8*q + 4*g + m;
                            if (row < N)
                                unsafeAtomicAdd(aggF + (size_t)row * OUT_C + o, C[4*q + m]);
                        }
                    }
                }
            }
        }
    }
}

// ---------------------------------------------------------------------------
extern "C" void kernel_launch(void* const* d_in, const int* in_sizes, int n_in,
                              void* d_out, int out_size, void* d_ws, size_t ws_size,
                              hipStream_t stream)
{
    const float* x  = (const float*)d_in[0];
    const int*   ei = (const int*)d_in[1];
    const float* ea = (const float*)d_in[2];

    const int E = in_sizes[2] / 4;
    const int N = in_sizes[0] / 10;
    const int* src = ei;
    const int* dst = ei + E;

    const float* p[4][6];   // w1, b1, w2, b2, root, bias
    for (int L = 0; L < 4; ++L)
        for (int j = 0; j < 6; ++j)
            p[L][j] = (const float*)d_in[3 + 6 * L + j];

    char* w = (char*)d_ws;
    auto carve = [&](size_t bytes) {
        char* q = w; w += (bytes + 255) & ~(size_t)255; return (void*)q;
    };
    _Float16* xin  = (_Float16*)carve((size_t)N * 8 * 2);
    _Float16* aggz = (_Float16*)carve((size_t)3 * N * 32 * 2); // agg0|agg1|agg2 f16
    _Float16* bswz = (_Float16*)carve((size_t)BSWZ_TOT * 2);
    _Float16* agg0 = aggz;
    _Float16* agg1 = aggz + (size_t)N * 32;
    _Float16* agg2 = aggz + (size_t)2 * N * 32;
    float* out  = (float*)d_out;

    Prm prm{};
    prm.x = x;
    for (int L = 0; L < 4; ++L) {
        prm.w2[L] = p[L][2]; prm.b2[L] = p[L][3];
        prm.root[L] = p[L][4]; prm.bias[L] = p[L][5];
    }
    prm.xin = xin; prm.bswz = bswz; prm.aggz = aggz; prm.outz = out; prm.N = N;

    const int NB8 = (N * 8 + 255) / 256;
    const int NZA = (N * 12 + 255) / 256;            // 3*N*32*2B / 16B uint4
    const int NZO = (N + 255) / 256;                 // N float2

    const int ntileE = (E + 31) / 32;
    const int ntileN = (N + 31) / 32;
    const int ntot   = ntileE + ntileN;
    int NB = (ntot + 7) / 8;                         // 8 waves / block
    if (NB > 512) NB = 512;                          // 2 blocks/CU co-resident

    // 5 dispatches total
    prep<<<452 + NB8 + NZA + NZO, 256, 0, stream>>>(prm, NB8, NZA, NZO);

    edge<8, 32><<<NB, 512, 0, stream>>>(             // layer 0
        xin, nullptr, src, dst, ea, p[0][0], p[0][1],
        bswz + 0 * 512, agg0, nullptr, E, N, ntileE, ntot);

    edge<32, 32><<<NB, 512, 0, stream>>>(            // layer 1
        nullptr, agg0, src, dst, ea, p[1][0], p[1][1],
        bswz + 19 * 512, agg1, nullptr, E, N, ntileE, ntot);

    edge<32, 32><<<NB, 512, 0, stream>>>(            // layer 2
        nullptr, agg1, src, dst, ea, p[2][0], p[2][1],
        bswz + 88 * 512, agg2, nullptr, E, N, ntileE, ntot);

    edge<32, 2><<<NB, 512, 0, stream>>>(             // layer 3 -> d_out
        nullptr, agg2, src, dst, ea, p[3][0], p[3][1],
        bswz + 157 * 512, nullptr, out, E, N, ntileE, ntot);
}